// Round 1
// baseline (314.783 us; speedup 1.0000x reference)
//
#include <hip/hip_runtime.h>
#include <hip/hip_bf16.h>

// Causal single-head attention, B=4, S=4096, D=128, fp32 in/out.
// Flash-attention v2 style: per block, BM=64 query rows; iterate BN=64 key
// tiles; QK^T and PV via bf16 MFMA 16x16x32; softmax in fp32 (exp2 domain,
// scale*log2e folded into Q at bf16-convert time).

#define B_   4
#define S_   4096
#define D_   128
#define BM   64
#define BN   64
#define KSTR 136   // 128 + 8 shorts pad: keeps 16B alignment, 2-way banks (free)
#define VSTR 72    // 64 + 8 shorts pad
#define PSTR 72    // 64 + 8 shorts pad

typedef __attribute__((ext_vector_type(8))) short bf16x8;
typedef __attribute__((ext_vector_type(4))) float f32x4;

__device__ __forceinline__ short f2bf(float x) {
    // round-to-nearest-even fp32 -> bf16 (no NaN inputs in this problem)
    unsigned u = __builtin_bit_cast(unsigned, x);
    unsigned r = (u + 0x7fffu + ((u >> 16) & 1u)) >> 16;
    return (short)r;
}

__device__ __forceinline__ float ex2(float x) { return __builtin_amdgcn_exp2f(x); }

__global__ __launch_bounds__(256) void fa_fwd(const float* __restrict__ Qg,
                                              const float* __restrict__ Kg,
                                              const float* __restrict__ Vg,
                                              float* __restrict__ Og)
{
    __shared__ short lk[BN * KSTR];     // K tile, row-major [n][d] bf16
    __shared__ short lv[D_ * VSTR];     // V tile, transposed [d][n] bf16
    __shared__ short lp[4 * 16 * PSTR]; // per-wave P tile [m][n] bf16

    const int tid  = threadIdx.x;
    const int wv   = tid >> 6;
    const int lane = tid & 63;
    const int m    = lane & 15;   // MFMA row/col within 16
    const int quad = lane >> 4;   // 0..3

    const int blk   = blockIdx.x;
    const int batch = blk & 3;
    const int t     = (S_ / BM - 1) - (blk >> 2);  // heavy q-tiles get low blockIdx

    const float SC = 0.12751740f;  // log2(e) / sqrt(128)

    // ---- Q fragments (A-operand layout: A[m=lane&15][k=quad*8+j]), scale folded
    bf16x8 qf[4];
    {
        const float* qp = Qg + ((size_t)batch * S_ + (size_t)t * BM + wv * 16 + m) * D_ + quad * 8;
#pragma unroll
        for (int c = 0; c < 4; ++c) {
            float4 a = *reinterpret_cast<const float4*>(qp + c * 32);
            float4 b = *reinterpret_cast<const float4*>(qp + c * 32 + 4);
            bf16x8 v;
            v[0] = f2bf(a.x * SC); v[1] = f2bf(a.y * SC);
            v[2] = f2bf(a.z * SC); v[3] = f2bf(a.w * SC);
            v[4] = f2bf(b.x * SC); v[5] = f2bf(b.y * SC);
            v[6] = f2bf(b.z * SC); v[7] = f2bf(b.w * SC);
            qf[c] = v;
        }
    }

    f32x4 acc[8];
#pragma unroll
    for (int i = 0; i < 8; ++i) acc[i] = (f32x4){0.f, 0.f, 0.f, 0.f};
    float mrun[4], lrun[4];
#pragma unroll
    for (int r = 0; r < 4; ++r) { mrun[r] = -__builtin_inff(); lrun[r] = 0.f; }

    short* pw = lp + wv * 16 * PSTR;   // wave-private P buffer

    for (int kt = 0; kt <= t; ++kt) {
        __syncthreads();  // previous iteration's LDS reads done before restage

        // ---- stage K tile: 64 rows x 128 cols fp32 -> bf16, row-major
        {
            const int r  = tid >> 2;   // 0..63
            const int qd = tid & 3;    // 32-col chunk
            const float* kp = Kg + ((size_t)batch * S_ + (size_t)kt * BN + r) * D_ + qd * 32;
            short* dst = lk + r * KSTR + qd * 32;
#pragma unroll
            for (int j = 0; j < 4; ++j) {
                float4 a = reinterpret_cast<const float4*>(kp)[2 * j];
                float4 b = reinterpret_cast<const float4*>(kp)[2 * j + 1];
                bf16x8 v;
                v[0] = f2bf(a.x); v[1] = f2bf(a.y); v[2] = f2bf(a.z); v[3] = f2bf(a.w);
                v[4] = f2bf(b.x); v[5] = f2bf(b.y); v[6] = f2bf(b.z); v[7] = f2bf(b.w);
                *reinterpret_cast<bf16x8*>(dst + j * 8) = v;
            }
        }
        // ---- stage V transposed: lv[d][n], packing n-pairs for b32 writes
        {
            const int np = tid & 31;   // n-pair: rows 2np, 2np+1
            const int dg = tid >> 5;   // 16-col group
            const float* vp = Vg + ((size_t)batch * S_ + (size_t)kt * BN + 2 * np) * D_ + dg * 16;
#pragma unroll
            for (int j = 0; j < 4; ++j) {
                float4 a = reinterpret_cast<const float4*>(vp)[j];
                float4 b = reinterpret_cast<const float4*>(vp + D_)[j];
                const int d0 = dg * 16 + 4 * j;
                *reinterpret_cast<short2*>(lv + (d0 + 0) * VSTR + 2 * np) = make_short2(f2bf(a.x), f2bf(b.x));
                *reinterpret_cast<short2*>(lv + (d0 + 1) * VSTR + 2 * np) = make_short2(f2bf(a.y), f2bf(b.y));
                *reinterpret_cast<short2*>(lv + (d0 + 2) * VSTR + 2 * np) = make_short2(f2bf(a.z), f2bf(b.z));
                *reinterpret_cast<short2*>(lv + (d0 + 3) * VSTR + 2 * np) = make_short2(f2bf(a.w), f2bf(b.w));
            }
        }
        __syncthreads();

        // ---- QK^T: S-tile 16x64 in C-layout (col=lane&15, row=quad*4+reg)
        f32x4 s[4];
#pragma unroll
        for (int nt = 0; nt < 4; ++nt) s[nt] = (f32x4){0.f, 0.f, 0.f, 0.f};
#pragma unroll
        for (int c = 0; c < 4; ++c) {
#pragma unroll
            for (int nt = 0; nt < 4; ++nt) {
                bf16x8 kf = *reinterpret_cast<const bf16x8*>(lk + (nt * 16 + m) * KSTR + c * 32 + quad * 8);
                s[nt] = __builtin_amdgcn_mfma_f32_16x16x32_bf16(qf[c], kf, s[nt], 0, 0, 0);
            }
        }

        // ---- causal mask (only the diagonal tile needs it)
        if (kt == t) {
            const int qloc = wv * 16 + quad * 4;
#pragma unroll
            for (int nt = 0; nt < 4; ++nt) {
                const int kloc = nt * 16 + m;
#pragma unroll
                for (int r = 0; r < 4; ++r)
                    if (kloc > qloc + r) s[nt][r] = -__builtin_inff();
            }
        }

        // ---- online softmax (exp2 domain; row r lives in 16 lanes sharing quad)
#pragma unroll
        for (int r = 0; r < 4; ++r) {
            float mx = fmaxf(fmaxf(s[0][r], s[1][r]), fmaxf(s[2][r], s[3][r]));
#pragma unroll
            for (int off = 1; off < 16; off <<= 1) mx = fmaxf(mx, __shfl_xor(mx, off));
            float mnew = fmaxf(mrun[r], mx);
            float al   = ex2(mrun[r] - mnew);   // 0 when mrun was -inf
            mrun[r] = mnew;
            float p0 = ex2(s[0][r] - mnew);
            float p1 = ex2(s[1][r] - mnew);
            float p2 = ex2(s[2][r] - mnew);
            float p3 = ex2(s[3][r] - mnew);
            s[0][r] = p0; s[1][r] = p1; s[2][r] = p2; s[3][r] = p3;
            float sum = (p0 + p1) + (p2 + p3);
#pragma unroll
            for (int off = 1; off < 16; off <<= 1) sum += __shfl_xor(sum, off);
            lrun[r] = lrun[r] * al + sum;
#pragma unroll
            for (int ct = 0; ct < 8; ++ct) acc[ct][r] *= al;
        }

        // ---- P: C-layout -> LDS -> A-layout (wave-private; same-wave DS ops
        //      are in-order, no barrier needed)
#pragma unroll
        for (int nt = 0; nt < 4; ++nt)
#pragma unroll
            for (int r = 0; r < 4; ++r)
                pw[(quad * 4 + r) * PSTR + nt * 16 + m] = f2bf(s[nt][r]);

        // ---- PV: O[16][128] += P[16][64] * V[64][128]
#pragma unroll
        for (int ks = 0; ks < 2; ++ks) {
            bf16x8 pf = *reinterpret_cast<const bf16x8*>(pw + m * PSTR + ks * 32 + quad * 8);
#pragma unroll
            for (int ct = 0; ct < 8; ++ct) {
                bf16x8 vf = *reinterpret_cast<const bf16x8*>(lv + (ct * 16 + m) * VSTR + ks * 32 + quad * 8);
                acc[ct] = __builtin_amdgcn_mfma_f32_16x16x32_bf16(pf, vf, acc[ct], 0, 0, 0);
            }
        }
    }

    // ---- epilogue: O = acc / l
    const size_t obase = ((size_t)batch * S_ + (size_t)t * BM + wv * 16 + quad * 4) * D_;
#pragma unroll
    for (int r = 0; r < 4; ++r) {
        float inv = 1.0f / lrun[r];
#pragma unroll
        for (int ct = 0; ct < 8; ++ct)
            Og[obase + (size_t)r * D_ + ct * 16 + m] = acc[ct][r] * inv;
    }
}

extern "C" void kernel_launch(void* const* d_in, const int* in_sizes, int n_in,
                              void* d_out, int out_size, void* d_ws, size_t ws_size,
                              hipStream_t stream) {
    const float* q = (const float*)d_in[0];
    const float* k = (const float*)d_in[1];
    const float* v = (const float*)d_in[2];
    float* o = (float*)d_out;
    dim3 grid(B_ * (S_ / BM));   // 256 blocks, 4 waves each
    fa_fwd<<<grid, 256, 0, stream>>>(q, k, v, o);
}

// Round 2
// 155.751 us; speedup vs baseline: 2.0211x; 2.0211x over previous
//
#include <hip/hip_runtime.h>

// Causal single-head attention, B=4, S=4096, D=128, fp32 in/out.
// R2: flash-decode split-K across blocks (R chunks per q-tile, partials in
// d_ws, merge kernel) + register-prefetch pipelining of K/V staging.
// QK^T and PV via bf16 MFMA 16x16x32; softmax fp32 in exp2 domain.

#define B_   4
#define S_   4096
#define D_   128
#define BM   64
#define BN   64
#define NT_  (S_ / BM)   // 64 q-tiles per batch
#define RMAX 4
#define KSTR 136   // 128 + 8 shorts: keeps 16B row alignment, 2-way banks (free)
#define VSTR 72    // 64 + 8
#define PSTR 72

typedef __attribute__((ext_vector_type(8))) short bf16x8;
typedef __attribute__((ext_vector_type(4))) float f32x4;

__device__ __forceinline__ short f2bf(float x) {
    unsigned u = __builtin_bit_cast(unsigned, x);
    unsigned r = (u + 0x7fffu + ((u >> 16) & 1u)) >> 16;
    return (short)r;
}
__device__ __forceinline__ float ex2(float x) { return __builtin_amdgcn_exp2f(x); }

struct StReg { float4 k[8]; float4 v[8]; };   // one K/V tile worth, per thread

__device__ __forceinline__ void stage_load(StReg& st, const float* __restrict__ Kg,
                                           const float* __restrict__ Vg,
                                           int batch, int kt, int tid) {
    const int r  = tid >> 2, qd = tid & 3;
    const float* kp = Kg + ((size_t)batch * S_ + (size_t)kt * BN + r) * D_ + qd * 32;
#pragma unroll
    for (int j = 0; j < 8; ++j) st.k[j] = reinterpret_cast<const float4*>(kp)[j];
    const int np = tid & 31, dg = tid >> 5;
    const float* vp = Vg + ((size_t)batch * S_ + (size_t)kt * BN + 2 * np) * D_ + dg * 16;
#pragma unroll
    for (int j = 0; j < 4; ++j) {
        st.v[2 * j]     = reinterpret_cast<const float4*>(vp)[j];
        st.v[2 * j + 1] = reinterpret_cast<const float4*>(vp + D_)[j];
    }
}

__device__ __forceinline__ void stage_store(const StReg& st, short* lk, short* lv, int tid) {
    const int r  = tid >> 2, qd = tid & 3;
    short* dst = lk + r * KSTR + qd * 32;
#pragma unroll
    for (int j = 0; j < 4; ++j) {
        float4 a = st.k[2 * j], b = st.k[2 * j + 1];
        bf16x8 v;
        v[0] = f2bf(a.x); v[1] = f2bf(a.y); v[2] = f2bf(a.z); v[3] = f2bf(a.w);
        v[4] = f2bf(b.x); v[5] = f2bf(b.y); v[6] = f2bf(b.z); v[7] = f2bf(b.w);
        *reinterpret_cast<bf16x8*>(dst + j * 8) = v;
    }
    const int np = tid & 31, dg = tid >> 5;
#pragma unroll
    for (int j = 0; j < 4; ++j) {
        float4 a = st.v[2 * j], b = st.v[2 * j + 1];
        const int d0 = dg * 16 + 4 * j;
        *reinterpret_cast<short2*>(lv + (d0 + 0) * VSTR + 2 * np) = make_short2(f2bf(a.x), f2bf(b.x));
        *reinterpret_cast<short2*>(lv + (d0 + 1) * VSTR + 2 * np) = make_short2(f2bf(a.y), f2bf(b.y));
        *reinterpret_cast<short2*>(lv + (d0 + 2) * VSTR + 2 * np) = make_short2(f2bf(a.z), f2bf(b.z));
        *reinterpret_cast<short2*>(lv + (d0 + 3) * VSTR + 2 * np) = make_short2(f2bf(a.w), f2bf(b.w));
    }
}

template<bool SPLIT>
__global__ __launch_bounds__(256) void fa_fwd(const float* __restrict__ Qg,
                                              const float* __restrict__ Kg,
                                              const float* __restrict__ Vg,
                                              float* __restrict__ Og,
                                              float* __restrict__ Op,
                                              float* __restrict__ Ml,
                                              int R)
{
    __shared__ short lk[BN * KSTR];
    __shared__ short lv[D_ * VSTR];
    __shared__ short lp[4 * 16 * PSTR];

    const int tid  = threadIdx.x;
    const int wv   = tid >> 6;
    const int lane = tid & 63;
    const int m    = lane & 15;
    const int quad = lane >> 4;

    int batch, t, lo, hi, chunk_id;
    {
        const int id = blockIdx.x;
        if (SPLIT) {
            batch = id & 3;
            int u = id >> 2;
            int tt = u / R;
            int r  = u - tt * R;
            t  = NT_ - 1 - tt;                 // heavy q-tiles dispatch first
            lo = r * (t + 1) / R;
            hi = (r + 1) * (t + 1) / R;
            chunk_id = (batch * NT_ + t) * R + r;
            if (lo >= hi) return;              // uniform: safe before barriers
        } else {
            batch = id & 3;
            t  = NT_ - 1 - (id >> 2);
            lo = 0; hi = t + 1; chunk_id = 0;
        }
    }

    const float SC = 0.12751740f;  // log2(e) / sqrt(128)

    bf16x8 qf[4];
    {
        const float* qp = Qg + ((size_t)batch * S_ + (size_t)t * BM + wv * 16 + m) * D_ + quad * 8;
#pragma unroll
        for (int c = 0; c < 4; ++c) {
            float4 a = *reinterpret_cast<const float4*>(qp + c * 32);
            float4 b = *reinterpret_cast<const float4*>(qp + c * 32 + 4);
            bf16x8 v;
            v[0] = f2bf(a.x * SC); v[1] = f2bf(a.y * SC);
            v[2] = f2bf(a.z * SC); v[3] = f2bf(a.w * SC);
            v[4] = f2bf(b.x * SC); v[5] = f2bf(b.y * SC);
            v[6] = f2bf(b.z * SC); v[7] = f2bf(b.w * SC);
            qf[c] = v;
        }
    }

    f32x4 acc[8];
#pragma unroll
    for (int i = 0; i < 8; ++i) acc[i] = (f32x4){0.f, 0.f, 0.f, 0.f};
    float mrun[4], lrun[4];
#pragma unroll
    for (int r = 0; r < 4; ++r) { mrun[r] = -__builtin_inff(); lrun[r] = 0.f; }

    short* pw = lp + wv * 16 * PSTR;

    StReg st;
    stage_load(st, Kg, Vg, batch, lo, tid);

    for (int kt = lo; kt < hi; ++kt) {
        __syncthreads();                        // prev iter's LDS reads done
        stage_store(st, lk, lv, tid);
        if (kt + 1 < hi) stage_load(st, Kg, Vg, batch, kt + 1, tid);  // in flight during compute
        __syncthreads();

        // ---- QK^T
        f32x4 s[4];
#pragma unroll
        for (int nt = 0; nt < 4; ++nt) s[nt] = (f32x4){0.f, 0.f, 0.f, 0.f};
#pragma unroll
        for (int c = 0; c < 4; ++c) {
#pragma unroll
            for (int nt = 0; nt < 4; ++nt) {
                bf16x8 kf = *reinterpret_cast<const bf16x8*>(lk + (nt * 16 + m) * KSTR + c * 32 + quad * 8);
                s[nt] = __builtin_amdgcn_mfma_f32_16x16x32_bf16(qf[c], kf, s[nt], 0, 0, 0);
            }
        }

        // ---- causal mask (diagonal tile only)
        if (kt == t) {
            const int qloc = wv * 16 + quad * 4;
#pragma unroll
            for (int nt = 0; nt < 4; ++nt) {
                const int kloc = nt * 16 + m;
#pragma unroll
                for (int r = 0; r < 4; ++r)
                    if (kloc > qloc + r) s[nt][r] = -__builtin_inff();
            }
        }

        // ---- online softmax (exp2 domain)
#pragma unroll
        for (int r = 0; r < 4; ++r) {
            float mx = fmaxf(fmaxf(s[0][r], s[1][r]), fmaxf(s[2][r], s[3][r]));
#pragma unroll
            for (int off = 1; off < 16; off <<= 1) mx = fmaxf(mx, __shfl_xor(mx, off));
            float mnew = fmaxf(mrun[r], mx);
            float al   = ex2(mrun[r] - mnew);
            mrun[r] = mnew;
            float p0 = ex2(s[0][r] - mnew);
            float p1 = ex2(s[1][r] - mnew);
            float p2 = ex2(s[2][r] - mnew);
            float p3 = ex2(s[3][r] - mnew);
            s[0][r] = p0; s[1][r] = p1; s[2][r] = p2; s[3][r] = p3;
            float sum = (p0 + p1) + (p2 + p3);
#pragma unroll
            for (int off = 1; off < 16; off <<= 1) sum += __shfl_xor(sum, off);
            lrun[r] = lrun[r] * al + sum;
#pragma unroll
            for (int ct = 0; ct < 8; ++ct) acc[ct][r] *= al;
        }

        // ---- P: C-layout -> wave-private LDS -> A-layout
#pragma unroll
        for (int nt = 0; nt < 4; ++nt)
#pragma unroll
            for (int r = 0; r < 4; ++r)
                pw[(quad * 4 + r) * PSTR + nt * 16 + m] = f2bf(s[nt][r]);

        // ---- PV
#pragma unroll
        for (int ks = 0; ks < 2; ++ks) {
            bf16x8 pf = *reinterpret_cast<const bf16x8*>(pw + m * PSTR + ks * 32 + quad * 8);
#pragma unroll
            for (int ct = 0; ct < 8; ++ct) {
                bf16x8 vf = *reinterpret_cast<const bf16x8*>(lv + (ct * 16 + m) * VSTR + ks * 32 + quad * 8);
                acc[ct] = __builtin_amdgcn_mfma_f32_16x16x32_bf16(pf, vf, acc[ct], 0, 0, 0);
            }
        }
    }

    const int row0 = wv * 16 + quad * 4;
    if (SPLIT) {
        float* ob = Op + (size_t)chunk_id * (BM * D_);
#pragma unroll
        for (int r = 0; r < 4; ++r)
#pragma unroll
            for (int ct = 0; ct < 8; ++ct)
                ob[(row0 + r) * D_ + ct * 16 + m] = acc[ct][r];
        if (m == 0) {
            float* mlb = Ml + (size_t)chunk_id * (BM * 2);
#pragma unroll
            for (int r = 0; r < 4; ++r) {
                mlb[(row0 + r) * 2]     = mrun[r];
                mlb[(row0 + r) * 2 + 1] = lrun[r];
            }
        }
    } else {
        const size_t obase = ((size_t)batch * S_ + (size_t)t * BM + row0) * D_;
#pragma unroll
        for (int r = 0; r < 4; ++r) {
            float inv = 1.0f / lrun[r];
#pragma unroll
            for (int ct = 0; ct < 8; ++ct)
                Og[obase + (size_t)r * D_ + ct * 16 + m] = acc[ct][r] * inv;
        }
    }
}

__global__ __launch_bounds__(256) void fa_merge(const float* __restrict__ Op,
                                                const float* __restrict__ Ml,
                                                float* __restrict__ Og, int R)
{
    const int id  = blockIdx.x;        // b*NT_ + t
    const int t   = id & (NT_ - 1);
    const int row = threadIdx.x >> 2;  // 0..63
    const int cg  = threadIdx.x & 3;   // 32-col group
    const size_t cbase = (size_t)id * R;

    float mg = -__builtin_inff();
    for (int r = 0; r < R; ++r) {
        int lo = r * (t + 1) / R, hi = (r + 1) * (t + 1) / R;
        if (lo < hi) mg = fmaxf(mg, Ml[(cbase + r) * (BM * 2) + row * 2]);
    }
    float l = 0.f;
    f32x4 a[8];
#pragma unroll
    for (int j = 0; j < 8; ++j) a[j] = (f32x4){0.f, 0.f, 0.f, 0.f};
    for (int r = 0; r < R; ++r) {
        int lo = r * (t + 1) / R, hi = (r + 1) * (t + 1) / R;
        if (lo >= hi) continue;
        float mr = Ml[(cbase + r) * (BM * 2) + row * 2];
        float lr = Ml[(cbase + r) * (BM * 2) + row * 2 + 1];
        float w  = ex2(mr - mg);
        l += lr * w;
        const f32x4* op = reinterpret_cast<const f32x4*>(Op + (cbase + r) * (BM * D_) + row * D_ + cg * 32);
#pragma unroll
        for (int j = 0; j < 8; ++j) a[j] += w * op[j];
    }
    float inv = 1.0f / l;
    f32x4* og = reinterpret_cast<f32x4*>(Og + (size_t)id * (BM * D_) + row * D_ + cg * 32);
#pragma unroll
    for (int j = 0; j < 8; ++j) og[j] = a[j] * inv;
}

extern "C" void kernel_launch(void* const* d_in, const int* in_sizes, int n_in,
                              void* d_out, int out_size, void* d_ws, size_t ws_size,
                              hipStream_t stream) {
    const float* q = (const float*)d_in[0];
    const float* k = (const float*)d_in[1];
    const float* v = (const float*)d_in[2];
    float* o = (float*)d_out;

    const size_t O_FLOATS  = (size_t)B_ * NT_ * BM * D_;   // per R-unit
    const size_t ML_FLOATS = (size_t)B_ * NT_ * BM * 2;
    const size_t PER_R     = (O_FLOATS + ML_FLOATS) * sizeof(float);  // ~8.52 MB

    int R = (int)(ws_size / PER_R);
    if (R > RMAX) R = RMAX;

    if (R >= 1) {
        float* Op = (float*)d_ws;
        float* Ml = Op + (size_t)R * O_FLOATS;
        fa_fwd<true><<<dim3(B_ * NT_ * R), 256, 0, stream>>>(q, k, v, nullptr, Op, Ml, R);
        fa_merge<<<dim3(B_ * NT_), 256, 0, stream>>>(Op, Ml, o, R);
    } else {
        fa_fwd<false><<<dim3(B_ * NT_), 256, 0, stream>>>(q, k, v, o, nullptr, nullptr, 1);
    }
}

// Round 3
// 134.888 us; speedup vs baseline: 2.3337x; 1.1547x over previous
//
#include <hip/hip_runtime.h>

// Causal single-head attention, B=4, S=4096, D=128, fp32 in/out.
// R3: prep kernel converts Q (scaled) + K + V^T to bf16 once into d_ws; K/V
// stored as 32KB per-tile LDS images with 16B-granule xor swizzle (conflict-
// free unpadded LDS reads). fa_fwd stages tiles via global_load_lds (async,
// double-buffered, issued after barrier so loads overlap compute). Merge
// kernel template-unrolled over R with 4 blocks/CU.

#define B_   4
#define S_   4096
#define D_   128
#define BM   64
#define BN   64
#define NT_  (S_ / BM)      // 64 q-tiles per batch
#define RMAX 4
#define PSTR 72
#define BLOB_SHORTS 16384   // 32 KB per (b,kt): [K img 16KB][V^T img 16KB]

typedef __attribute__((ext_vector_type(8))) short bf16x8;
typedef __attribute__((ext_vector_type(4))) float f32x4;

__device__ __forceinline__ short f2bf(float x) {
    unsigned u = __builtin_bit_cast(unsigned, x);
    unsigned r = (u + 0x7fffu + ((u >> 16) & 1u)) >> 16;
    return (short)r;
}
__device__ __forceinline__ float ex2(float x) { return __builtin_amdgcn_exp2f(x); }

__device__ __forceinline__ void gl_lds16(const short* g, short* l) {
    __builtin_amdgcn_global_load_lds(
        (const __attribute__((address_space(1))) unsigned int*)g,
        (__attribute__((address_space(3))) unsigned int*)l, 16, 0, 0);
}

// ---------------- prep: fp32 -> bf16, build swizzled tile images ----------
// K image: row n (64), granule p (16 of 8 bf16); source granule G stored at
//   p = (G&8) | ((G&7) ^ (n&7)).
// V image: row d (128), granule p (8); source granule G at p = G ^ (d&7),
//   where granule G of row d = V[kt*64 + G*8 + i][d], i=0..7.
__global__ __launch_bounds__(256) void prep(const float* __restrict__ Qg,
                                            const float* __restrict__ Kg,
                                            const float* __restrict__ Vg,
                                            short* __restrict__ Qbf,
                                            short* __restrict__ KV)
{
    __shared__ short vt[64][136];   // 136: 16B-aligned rows, 4-bank rotation

    const int x = blockIdx.x;
    const int b = x & 3, tile = x >> 2;
    const int tid = threadIdx.x;
    const int n = tid >> 2, q = tid & 3;
    const size_t rowbase = ((size_t)b * S_ + (size_t)tile * 64 + n) * D_ + q * 32;
    short* blob = KV + (size_t)(b * NT_ + tile) * BLOB_SHORTS;

    const float SC = 0.12751740f;   // log2(e)/sqrt(128)
    // Q: scale + convert, plain layout
    {
        const float4* src = reinterpret_cast<const float4*>(Qg + rowbase);
        short* dst = Qbf + rowbase;
#pragma unroll
        for (int j = 0; j < 4; ++j) {
            float4 a = src[2 * j], c = src[2 * j + 1];
            bf16x8 v;
            v[0] = f2bf(a.x * SC); v[1] = f2bf(a.y * SC); v[2] = f2bf(a.z * SC); v[3] = f2bf(a.w * SC);
            v[4] = f2bf(c.x * SC); v[5] = f2bf(c.y * SC); v[6] = f2bf(c.z * SC); v[7] = f2bf(c.w * SC);
            *reinterpret_cast<bf16x8*>(dst + j * 8) = v;
        }
    }
    // K: convert + swizzle into image
    {
        const float4* src = reinterpret_cast<const float4*>(Kg + rowbase);
#pragma unroll
        for (int j = 0; j < 4; ++j) {
            float4 a = src[2 * j], c = src[2 * j + 1];
            bf16x8 v;
            v[0] = f2bf(a.x); v[1] = f2bf(a.y); v[2] = f2bf(a.z); v[3] = f2bf(a.w);
            v[4] = f2bf(c.x); v[5] = f2bf(c.y); v[6] = f2bf(c.z); v[7] = f2bf(c.w);
            const int G = q * 4 + j;
            const int p = (G & 8) | ((G & 7) ^ (n & 7));
            *reinterpret_cast<bf16x8*>(blob + n * 128 + p * 8) = v;
        }
    }
    // V: convert into LDS, then gather transposed granules
    {
        const float4* src = reinterpret_cast<const float4*>(Vg + rowbase);
#pragma unroll
        for (int j = 0; j < 4; ++j) {
            float4 a = src[2 * j], c = src[2 * j + 1];
            bf16x8 v;
            v[0] = f2bf(a.x); v[1] = f2bf(a.y); v[2] = f2bf(a.z); v[3] = f2bf(a.w);
            v[4] = f2bf(c.x); v[5] = f2bf(c.y); v[6] = f2bf(c.z); v[7] = f2bf(c.w);
            *reinterpret_cast<bf16x8*>(&vt[n][q * 32 + j * 8]) = v;
        }
    }
    __syncthreads();
    {
        const int d = tid >> 1, jj = tid & 1;
#pragma unroll
        for (int j = 0; j < 4; ++j) {
            const int G = jj * 4 + j;
            bf16x8 g;
#pragma unroll
            for (int i = 0; i < 8; ++i) g[i] = vt[G * 8 + i][d];
            const int p = G ^ (d & 7);
            *reinterpret_cast<bf16x8*>(blob + 8192 + d * 64 + p * 8) = g;
        }
    }
}

// ---------------- fa_fwd ---------------------------------------------------
template<bool SPLIT>
__global__ __launch_bounds__(256) void fa_fwd(const short* __restrict__ Qbf,
                                              const short* __restrict__ KV,
                                              float* __restrict__ Og,
                                              float* __restrict__ Op,
                                              float* __restrict__ Ml,
                                              int R)
{
    __shared__ short lkv[2][BLOB_SHORTS];   // 64 KB double buffer
    __shared__ short lp[4 * 16 * PSTR];     // per-wave P tiles

    const int tid  = threadIdx.x;
    const int wv   = tid >> 6;
    const int lane = tid & 63;
    const int m    = lane & 15;
    const int quad = lane >> 4;
    const int m7   = m & 7;

    int batch, t, lo, hi, chunk_id;
    {
        const int id = blockIdx.x;
        batch = id & 3;
        if (SPLIT) {
            int u = id >> 2;
            int tt = u / R;
            int r  = u - tt * R;
            t  = NT_ - 1 - tt;                 // heavy q-tiles dispatch first
            lo = r * (t + 1) / R;
            hi = (r + 1) * (t + 1) / R;
            chunk_id = (batch * NT_ + t) * R + r;
            if (lo >= hi) return;              // block-uniform, before barriers
        } else {
            t  = NT_ - 1 - (id >> 2);
            lo = 0; hi = t + 1; chunk_id = 0;
        }
    }

    // Q fragments (bf16, pre-scaled): A[m][k=quad*8+j]
    bf16x8 qf[4];
    {
        const short* qp = Qbf + ((size_t)batch * S_ + (size_t)t * BM + wv * 16 + m) * D_ + quad * 8;
#pragma unroll
        for (int c = 0; c < 4; ++c)
            qf[c] = *reinterpret_cast<const bf16x8*>(qp + c * 32);
    }

    f32x4 acc[8];
#pragma unroll
    for (int i = 0; i < 8; ++i) acc[i] = (f32x4){0.f, 0.f, 0.f, 0.f};
    float mrun[4], lrun[4];
#pragma unroll
    for (int r = 0; r < 4; ++r) { mrun[r] = -__builtin_inff(); lrun[r] = 0.f; }

    short* pw = lp + wv * 16 * PSTR;

    // async stage: this wave copies its contiguous 8 KB of the 32 KB blob
    const size_t tilebase = (size_t)batch * NT_ * BLOB_SHORTS;
#define STAGE(KT, BUF) do {                                                   \
        const short* g_ = KV + tilebase + (size_t)(KT) * BLOB_SHORTS          \
                          + wv * 4096 + lane * 8;                             \
        short* l_ = (BUF) + wv * 4096;                                        \
        _Pragma("unroll")                                                     \
        for (int c_ = 0; c_ < 8; ++c_)                                        \
            gl_lds16(g_ + c_ * 512, l_ + c_ * 512);                           \
    } while (0)

    STAGE(lo, lkv[0]);

    for (int kt = lo; kt < hi; ++kt) {
        short* cur = lkv[(kt - lo) & 1];
        short* nxt = lkv[(kt - lo + 1) & 1];
        __syncthreads();   // drains vmcnt(0): cur complete; prev reads done
        if (kt + 1 < hi) STAGE(kt + 1, nxt);   // in flight during compute

        const short* lk = cur;            // K image: row n, swizzled granules
        const short* lv = cur + 8192;     // V image: row d, swizzled granules

        // ---- QK^T: S-tile 16x64, C-layout (col=lane&15, row=quad*4+reg)
        f32x4 s[4];
#pragma unroll
        for (int nt = 0; nt < 4; ++nt) s[nt] = (f32x4){0.f, 0.f, 0.f, 0.f};
#pragma unroll
        for (int c = 0; c < 4; ++c) {
            const int p = ((c >> 1) * 8) | ((((c & 1) * 4) | quad) ^ m7);
#pragma unroll
            for (int nt = 0; nt < 4; ++nt) {
                bf16x8 kf = *reinterpret_cast<const bf16x8*>(lk + nt * 2048 + m * 128 + p * 8);
                s[nt] = __builtin_amdgcn_mfma_f32_16x16x32_bf16(qf[c], kf, s[nt], 0, 0, 0);
            }
        }

        // ---- causal mask (diagonal tile only)
        if (kt == t) {
            const int qloc = wv * 16 + quad * 4;
#pragma unroll
            for (int nt = 0; nt < 4; ++nt) {
                const int kloc = nt * 16 + m;
#pragma unroll
                for (int r = 0; r < 4; ++r)
                    if (kloc > qloc + r) s[nt][r] = -__builtin_inff();
            }
        }

        // ---- online softmax (exp2 domain)
#pragma unroll
        for (int r = 0; r < 4; ++r) {
            float mx = fmaxf(fmaxf(s[0][r], s[1][r]), fmaxf(s[2][r], s[3][r]));
#pragma unroll
            for (int off = 1; off < 16; off <<= 1) mx = fmaxf(mx, __shfl_xor(mx, off));
            float mnew = fmaxf(mrun[r], mx);
            float al   = ex2(mrun[r] - mnew);
            mrun[r] = mnew;
            float p0 = ex2(s[0][r] - mnew);
            float p1 = ex2(s[1][r] - mnew);
            float p2 = ex2(s[2][r] - mnew);
            float p3 = ex2(s[3][r] - mnew);
            s[0][r] = p0; s[1][r] = p1; s[2][r] = p2; s[3][r] = p3;
            float sum = (p0 + p1) + (p2 + p3);
#pragma unroll
            for (int off = 1; off < 16; off <<= 1) sum += __shfl_xor(sum, off);
            lrun[r] = lrun[r] * al + sum;
#pragma unroll
            for (int ct = 0; ct < 8; ++ct) acc[ct][r] *= al;
        }

        // ---- P: C-layout -> wave-private LDS -> A-layout
#pragma unroll
        for (int nt = 0; nt < 4; ++nt)
#pragma unroll
            for (int r = 0; r < 4; ++r)
                pw[(quad * 4 + r) * PSTR + nt * 16 + m] = f2bf(s[nt][r]);

        // ---- PV: O[16][128] += P[16][64] * V[64][128]
#pragma unroll
        for (int ks = 0; ks < 2; ++ks) {
            bf16x8 pf = *reinterpret_cast<const bf16x8*>(pw + m * PSTR + ks * 32 + quad * 8);
            const int p = (ks * 4 + quad) ^ m7;
#pragma unroll
            for (int ct = 0; ct < 8; ++ct) {
                bf16x8 vf = *reinterpret_cast<const bf16x8*>(lv + ct * 1024 + m * 64 + p * 8);
                acc[ct] = __builtin_amdgcn_mfma_f32_16x16x32_bf16(pf, vf, acc[ct], 0, 0, 0);
            }
        }
    }
#undef STAGE

    const int row0 = wv * 16 + quad * 4;
    if (SPLIT) {
        float* ob = Op + (size_t)chunk_id * (BM * D_);
#pragma unroll
        for (int r = 0; r < 4; ++r)
#pragma unroll
            for (int ct = 0; ct < 8; ++ct)
                ob[(row0 + r) * D_ + ct * 16 + m] = acc[ct][r];
        if (m == 0) {
            float* mlb = Ml + (size_t)chunk_id * (BM * 2);
#pragma unroll
            for (int r = 0; r < 4; ++r) {
                mlb[(row0 + r) * 2]     = mrun[r];
                mlb[(row0 + r) * 2 + 1] = lrun[r];
            }
        }
    } else {
        const size_t obase = ((size_t)batch * S_ + (size_t)t * BM + row0) * D_;
#pragma unroll
        for (int r = 0; r < 4; ++r) {
            float inv = 1.0f / lrun[r];
#pragma unroll
            for (int ct = 0; ct < 8; ++ct)
                Og[obase + (size_t)r * D_ + ct * 16 + m] = acc[ct][r] * inv;
        }
    }
}

// ---------------- merge ----------------------------------------------------
template<int RR>
__global__ __launch_bounds__(256) void fa_merge(const float* __restrict__ Op,
                                                const float* __restrict__ Ml,
                                                float* __restrict__ Og)
{
    const int x   = blockIdx.x;
    const int btq = x >> 2;                 // b*NT + t
    const int seg = x & 3;
    const int t   = btq & (NT_ - 1);
    const int row = seg * 16 + (threadIdx.x >> 4);
    const int cg  = threadIdx.x & 15;       // 8 floats per thread
    const size_t cbase = (size_t)btq * RR;

    float mg = -__builtin_inff();
#pragma unroll
    for (int r = 0; r < RR; ++r) {
        int lo = r * (t + 1) / RR, hi = (r + 1) * (t + 1) / RR;
        if (lo < hi) mg = fmaxf(mg, Ml[(cbase + r) * (BM * 2) + row * 2]);
    }
    float l = 0.f;
    f32x4 a0 = (f32x4){0.f, 0.f, 0.f, 0.f}, a1 = a0;
#pragma unroll
    for (int r = 0; r < RR; ++r) {
        int lo = r * (t + 1) / RR, hi = (r + 1) * (t + 1) / RR;
        if (lo >= hi) continue;
        float mr = Ml[(cbase + r) * (BM * 2) + row * 2];
        float lr = Ml[(cbase + r) * (BM * 2) + row * 2 + 1];
        float w  = ex2(mr - mg);
        l += lr * w;
        const f32x4* op = reinterpret_cast<const f32x4*>(Op + (cbase + r) * (BM * D_) + row * D_ + cg * 8);
        a0 += w * op[0]; a1 += w * op[1];
    }
    float inv = 1.0f / l;
    f32x4* og = reinterpret_cast<f32x4*>(Og + (size_t)btq * (BM * D_) + row * D_ + cg * 8);
    og[0] = a0 * inv; og[1] = a1 * inv;
}

extern "C" void kernel_launch(void* const* d_in, const int* in_sizes, int n_in,
                              void* d_out, int out_size, void* d_ws, size_t ws_size,
                              hipStream_t stream) {
    const float* q = (const float*)d_in[0];
    const float* k = (const float*)d_in[1];
    const float* v = (const float*)d_in[2];
    float* o = (float*)d_out;

    const size_t QBF_BYTES = (size_t)B_ * S_ * D_ * 2;              // 4 MB
    const size_t KV_BYTES  = (size_t)B_ * NT_ * BLOB_SHORTS * 2;    // 8 MB
    const size_t PREFIX    = QBF_BYTES + KV_BYTES;                  // 12 MB
    const size_t O_FLOATS  = (size_t)B_ * NT_ * BM * D_;
    const size_t ML_FLOATS = (size_t)B_ * NT_ * BM * 2;
    const size_t PER_R     = (O_FLOATS + ML_FLOATS) * sizeof(float);

    char* ws = (char*)d_ws;
    short* Qbf = (short*)ws;
    short* KV  = (short*)(ws + QBF_BYTES);

    int R = 0;
    if (ws_size > PREFIX) {
        R = (int)((ws_size - PREFIX) / PER_R);
        if (R > RMAX) R = RMAX;
    }

    prep<<<dim3(B_ * NT_), 256, 0, stream>>>(q, k, v, Qbf, KV);

    if (R >= 1) {
        float* Op = (float*)(ws + PREFIX);
        float* Ml = Op + (size_t)R * O_FLOATS;
        fa_fwd<true><<<dim3(B_ * NT_ * R), 256, 0, stream>>>(Qbf, KV, nullptr, Op, Ml, R);
        switch (R) {
            case 1: fa_merge<1><<<dim3(B_ * NT_ * 4), 256, 0, stream>>>(Op, Ml, o); break;
            case 2: fa_merge<2><<<dim3(B_ * NT_ * 4), 256, 0, stream>>>(Op, Ml, o); break;
            case 3: fa_merge<3><<<dim3(B_ * NT_ * 4), 256, 0, stream>>>(Op, Ml, o); break;
            default: fa_merge<4><<<dim3(B_ * NT_ * 4), 256, 0, stream>>>(Op, Ml, o); break;
        }
    } else {
        fa_fwd<false><<<dim3(B_ * NT_), 256, 0, stream>>>(Qbf, KV, o, nullptr, nullptr, 1);
    }
}